// Round 1
// baseline (834.592 us; speedup 1.0000x reference)
//
#include <hip/hip_runtime.h>

typedef unsigned int u32;
typedef unsigned long long u64;

// ---------------------------------------------------------------------------
// Output layout (float32, 414 elems):
//  [0..3]    confmat [tn, fp, fn, tp]
//  [4]       map_ (= ap)
//  [5..105]  prec_t (101)
//  [106..206] rec_t (101)
//  [207..307] ths (101)
//  [308..408] spec_t (101)
//  [409] recall  [410] precision  [411] specificity  [412] accuracy  [413] loss_out
//
// Workspace layout (8-byte aligned):
//  fineHist:  K * 8          (u64 packed: low32 = count, high32 = posCount)
//  blockSums: S * 8          (u64 packed, descending-chunk sums -> exclusive offsets)
//  apPartial: S * 8          (double per chunk)
//  counters:  208 * 4        (u32: conf[4], thrAll[102], thrPos[102])
// ---------------------------------------------------------------------------

static __device__ __forceinline__ float safe_div_f(float a, float b) {
    return (b > 0.0f) ? (a / fmaxf(b, 1.0f)) : 0.0f;
}

static __device__ __forceinline__ void process_elem(
    float l0, float l1, int lbl,
    u32* __restrict__ confReg,            // 4 per-thread register counters
    u32* __restrict__ sThrAll, u32* __restrict__ sThrPos,
    u64* __restrict__ fineHist, int K, float Kf)
{
    float m  = fmaxf(l0, l1);
    float e0 = expf(l0 - m);
    float e1 = expf(l1 - m);
    int pred = (e1 > e0) ? 1 : 0;           // argmax(probas): ties -> 0
    float p1 = e1 / (e0 + e1);

    confReg[(lbl << 1) | pred] += 1u;

    // smallest k in [0,100] with p1 <= (float)k * 0.01f ; 101 if none
    int k = (int)ceilf(p1 * 100.0f);
    if (k < 0) k = 0;
    if (k > 101) k = 101;
    while (k > 0 && p1 <= (float)(k - 1) * 0.01f) --k;
    while (k <= 100 && p1 > (float)k * 0.01f) ++k;
    atomicAdd(&sThrAll[k], 1u);
    if (lbl) atomicAdd(&sThrPos[k], 1u);

    int b = (int)(p1 * Kf);
    if (b >= K) b = K - 1;
    if (b < 0) b = 0;
    atomicAdd(&fineHist[b], 1ULL + ((u64)(u32)lbl << 32));
}

__global__ void __launch_bounds__(256)
main_pass(const float* __restrict__ logits, const int* __restrict__ targets,
          int N, u64* __restrict__ fineHist, int K,
          u32* __restrict__ counters)
{
    __shared__ u32 sConf[4];
    __shared__ u32 sThrAll[102];
    __shared__ u32 sThrPos[102];
    const int t = threadIdx.x;
    if (t < 4) sConf[t] = 0;
    for (int i = t; i < 102; i += blockDim.x) { sThrAll[i] = 0; sThrPos[i] = 0; }
    __syncthreads();

    const float Kf = (float)K;
    const int nPairs = N >> 1;
    const int gid = blockIdx.x * blockDim.x + t;
    const int stride = gridDim.x * blockDim.x;
    const float4* __restrict__ lp = (const float4*)logits;
    const int2*   __restrict__ tg = (const int2*)targets;

    u32 confReg[4] = {0u, 0u, 0u, 0u};

    for (int i = gid; i < nPairs; i += stride) {
        float4 v = lp[i];
        int2   lab = tg[i];
        process_elem(v.x, v.y, lab.x, confReg, sThrAll, sThrPos, fineHist, K, Kf);
        process_elem(v.z, v.w, lab.y, confReg, sThrAll, sThrPos, fineHist, K, Kf);
    }
    if (gid == 0 && (N & 1)) {
        int last = N - 1;
        process_elem(logits[2 * last], logits[2 * last + 1], targets[last],
                     confReg, sThrAll, sThrPos, fineHist, K, Kf);
    }

    #pragma unroll
    for (int c = 0; c < 4; ++c)
        if (confReg[c]) atomicAdd(&sConf[c], confReg[c]);
    __syncthreads();

    if (t < 4 && sConf[t]) atomicAdd(&counters[t], sConf[t]);
    for (int i = t; i < 102; i += blockDim.x) {
        if (sThrAll[i]) atomicAdd(&counters[4 + i],   sThrAll[i]);
        if (sThrPos[i]) atomicAdd(&counters[106 + i], sThrPos[i]);
    }
}

// Sum each descending-order chunk of 1024 bins -> blockSums[c]
__global__ void __launch_bounds__(1024)
chunk_sums(const u64* __restrict__ fineHist, int K, u64* __restrict__ blockSums)
{
    __shared__ u64 sh[1024];
    const int t = threadIdx.x;
    const int d = blockIdx.x * 1024 + t;
    u64 v = (d < K) ? fineHist[K - 1 - d] : 0ULL;
    sh[t] = v;
    __syncthreads();
    for (int off = 512; off > 0; off >>= 1) {
        if (t < off) sh[t] += sh[t + off];
        __syncthreads();
    }
    if (t == 0) blockSums[blockIdx.x] = sh[0];
}

// Exclusive scan of blockSums[0..S-1] in place (single block)
__global__ void __launch_bounds__(1024)
scan_sums(u64* __restrict__ blockSums, int S)
{
    __shared__ u64 sh[1024];
    const int t = threadIdx.x;
    u64 own = (t < S) ? blockSums[t] : 0ULL;
    sh[t] = own;
    __syncthreads();
    for (int off = 1; off < 1024; off <<= 1) {
        u64 v = (t >= off) ? sh[t - off] : 0ULL;
        __syncthreads();
        sh[t] += v;
        __syncthreads();
    }
    if (t < S) blockSums[t] = sh[t] - own;
}

// Per-bin AP contributions: descending traversal with exclusive (Nb, Pb)
__global__ void __launch_bounds__(1024)
ap_kernel(const u64* __restrict__ fineHist, int K,
          const u64* __restrict__ blockOffsets, double* __restrict__ apPartial)
{
    __shared__ u64 sh[1024];
    __shared__ double sd[1024];
    const int t = threadIdx.x;
    const int d = blockIdx.x * 1024 + t;
    u64 h = (d < K) ? fineHist[K - 1 - d] : 0ULL;
    sh[t] = h;
    __syncthreads();
    for (int off = 1; off < 1024; off <<= 1) {
        u64 v = (t >= off) ? sh[t - off] : 0ULL;
        __syncthreads();
        sh[t] += v;
        __syncthreads();
    }
    u64 excl = blockOffsets[blockIdx.x] + (sh[t] - h);
    u32 Cv = (u32)h;
    u32 Pv = (u32)(h >> 32);
    double Nb = (double)(u32)excl;          // total count in strictly-higher bins
    double Pb = (double)(u32)(excl >> 32);  // positives in strictly-higher bins
    double contrib = 0.0;
    if (Pv > 0u) {
        double ratio = (double)Cv / (double)Pv;
        for (u32 j = 1; j <= Pv; ++j) {
            double rank = Nb + ((double)j - 0.5) * ratio + 0.5;
            contrib += (Pb + (double)j) / rank;
        }
    }
    sd[t] = contrib;
    __syncthreads();
    for (int off = 512; off > 0; off >>= 1) {
        if (t < off) sd[t] += sd[t + off];
        __syncthreads();
    }
    if (t == 0) apPartial[blockIdx.x] = sd[0];
}

__global__ void __launch_bounds__(128)
finalize(const u32* __restrict__ counters, const double* __restrict__ apPartial, int S,
         const float* __restrict__ loss, int N, float* __restrict__ out)
{
    __shared__ float sIdx[101];
    __shared__ float sFn[101];
    __shared__ float sScal[2]; // totPosF, nF
    const int t = threadIdx.x;
    if (t == 0) {
        float tn0 = (float)counters[0], fp0 = (float)counters[1];
        float fn0 = (float)counters[2], tp0 = (float)counters[3];
        u32 accA = 0u, accP = 0u;
        for (int k = 0; k <= 100; ++k) {
            accA += counters[4 + k];
            accP += counters[106 + k];
            sIdx[k] = (float)accA;
            sFn[k]  = (float)accP;
        }
        double s = 0.0;
        for (int c = 0; c < S; ++c) s += apPartial[c];
        u32 tpos = counters[2] + counters[3];
        double denom = (tpos > 0u) ? (double)tpos : 1.0;
        float ap = (float)(s / denom);
        float nF = (float)N;

        out[0] = tn0; out[1] = fp0; out[2] = fn0; out[3] = tp0;
        out[4] = ap;
        out[409] = safe_div_f(tp0, tp0 + fn0);   // recall
        out[410] = safe_div_f(tp0, tp0 + fp0);   // precision
        out[411] = safe_div_f(tn0, tn0 + fp0);   // specificity
        out[412] = (tp0 + tn0) / nF;             // accuracy
        out[413] = (loss[0] + loss[1] + loss[2] + loss[3]) * 0.25f;
        sScal[0] = fn0 + tp0;
        sScal[1] = nF;
    }
    __syncthreads();
    if (t < 101) {
        float totPos = sScal[0], nF = sScal[1];
        float idx_f = sIdx[t], fn_t = sFn[t];
        float tp_t = totPos - fn_t;
        float tn_t = idx_f - fn_t;
        float fp_t = nF - idx_f - tp_t;
        out[5 + t]   = safe_div_f(tp_t, tp_t + fp_t);  // prec_t
        out[106 + t] = safe_div_f(tp_t, tp_t + fn_t);  // rec_t
        out[207 + t] = (float)t * 0.01f;               // ths
        out[308 + t] = safe_div_f(tn_t, tn_t + fp_t);  // spec_t
    }
}

extern "C" void kernel_launch(void* const* d_in, const int* in_sizes, int n_in,
                              void* d_out, int out_size, void* d_ws, size_t ws_size,
                              hipStream_t stream)
{
    const float* logits  = (const float*)d_in[0];
    const int*   targets = (const int*)d_in[1];
    const float* loss    = (const float*)d_in[2];
    const int N = in_sizes[1];

    // Pick fine-histogram size K (power of two) that fits the workspace.
    int K = 1 << 20;
    for (;;) {
        int S = K / 1024; if (S < 1) S = 1;
        size_t need = (size_t)K * 8 + (size_t)S * 16 + 832;
        if (need <= ws_size || K <= 1024) break;
        K >>= 1;
    }
    int S = K / 1024; if (S < 1) S = 1;

    char* ws = (char*)d_ws;
    u64*    fineHist  = (u64*)ws;
    u64*    blockSums = (u64*)(ws + (size_t)K * 8);
    double* apPartial = (double*)(ws + (size_t)K * 8 + (size_t)S * 8);
    u32*    counters  = (u32*)(ws + (size_t)K * 8 + (size_t)S * 16);
    size_t zeroBytes = (size_t)K * 8 + (size_t)S * 16 + 832;

    hipMemsetAsync(d_ws, 0, zeroBytes, stream);

    main_pass<<<2048, 256, 0, stream>>>(logits, targets, N, fineHist, K, counters);
    chunk_sums<<<S, 1024, 0, stream>>>(fineHist, K, blockSums);
    scan_sums<<<1, 1024, 0, stream>>>(blockSums, S);
    ap_kernel<<<S, 1024, 0, stream>>>(fineHist, K, blockSums, apPartial);
    finalize<<<1, 128, 0, stream>>>(counters, apPartial, S, loss, N, (float*)d_out);
}

// Round 2
// 105.717 us; speedup vs baseline: 7.8946x; 7.8946x over previous
//
#include <hip/hip_runtime.h>

typedef unsigned int u32;
typedef unsigned long long u64;

// ---------------------------------------------------------------------------
// Output layout (float32, 414 elems):
//  [0..3]    confmat [tn, fp, fn, tp]
//  [4]       map_ (= ap)
//  [5..105]  prec_t (101)
//  [106..206] rec_t (101)
//  [207..307] ths (101)
//  [308..408] spec_t (101)
//  [409] recall  [410] precision  [411] specificity  [412] accuracy  [413] loss_out
//
// Workspace layout (8-byte aligned):
//  partials:  NB * K * 4   (u32 packed per block: count | pos<<16)
//  fineHist:  K * 8        (u64 packed: count | pos<<32)
//  blockSums: S * 8        (u64, descending-chunk sums -> exclusive offsets)
//  apPartial: S * 8        (double per chunk)
//  counters:  208 * 4      (u32: [0]=tpSum [1]=lblSum [2]=predSum [3]=unused,
//                                [4..105]=thrAll, [106..207]=thrPos)
// ---------------------------------------------------------------------------

#define KMAX   32768
#define TPB    1024
#define NBLK   256
#define CHUNK  256

static __device__ __forceinline__ float safe_div_f(float a, float b) {
    return (b > 0.0f) ? (a / fmaxf(b, 1.0f)) : 0.0f;
}

static __device__ __forceinline__ void proc(
    float l0, float l1, int lbl, int K, float Kf,
    u32& tp, u32& lblS, u32& predS,
    u32* __restrict__ sThr, u32* __restrict__ fineLDS)
{
    float d = l1 - l0;
    u32 pred = (d > 0.0f) ? 1u : 0u;            // argmax: ties -> 0
    float e = __expf(-fabsf(d));                // in (0,1]
    float pl = e / (1.0f + e);                  // min(p1, 1-p1)
    float p1 = pred ? (1.0f - pl) : pl;

    tp    += ((u32)lbl & pred);
    lblS  += (u32)lbl;
    predS += pred;

    u32 val = 1u + ((u32)lbl << 16);

    // smallest k in [0,100] with p1 <= (float)k * 0.01f ; 101 if none
    int k = (int)ceilf(p1 * 100.0f);
    k = min(max(k, 0), 101);
    if (k > 0 && p1 <= (float)(k - 1) * 0.01f) --k;
    else if (k <= 100 && p1 > (float)k * 0.01f) ++k;
    atomicAdd(&sThr[k], val);

    int b = (int)(p1 * Kf);
    b = max(min(b, K - 1), 0);
    atomicAdd(&fineLDS[b], val);
}

__global__ void __launch_bounds__(TPB)
main_pass(const float* __restrict__ logits, const int* __restrict__ targets,
          int N, u32* __restrict__ partials, int K,
          u32* __restrict__ counters)
{
    __shared__ u32 fineLDS[KMAX];
    __shared__ u32 sThr[102];
    __shared__ u32 sConf[3];

    const int t = threadIdx.x;
    for (int i = t; i < K; i += TPB) fineLDS[i] = 0u;
    if (t < 102) sThr[t] = 0u;
    if (t < 3)   sConf[t] = 0u;
    __syncthreads();

    const float Kf = (float)K;
    const int nPairs = N >> 1;
    const int gid = blockIdx.x * TPB + t;
    const int stride = gridDim.x * TPB;
    const float4* __restrict__ lp = (const float4*)logits;
    const int2*   __restrict__ tg = (const int2*)targets;

    u32 tp = 0u, lblS = 0u, predS = 0u;

    for (int i = gid; i < nPairs; i += stride) {
        float4 v = lp[i];
        int2 lab = tg[i];
        proc(v.x, v.y, lab.x, K, Kf, tp, lblS, predS, sThr, fineLDS);
        proc(v.z, v.w, lab.y, K, Kf, tp, lblS, predS, sThr, fineLDS);
    }
    if (gid == 0 && (N & 1)) {
        int last = N - 1;
        proc(logits[2 * last], logits[2 * last + 1], targets[last],
             K, Kf, tp, lblS, predS, sThr, fineLDS);
    }

    // wave-level reduce of the 3 scalar counters, then LDS, then global
    #pragma unroll
    for (int off = 32; off > 0; off >>= 1) {
        tp    += __shfl_down(tp, off);
        lblS  += __shfl_down(lblS, off);
        predS += __shfl_down(predS, off);
    }
    if ((t & 63) == 0) {
        atomicAdd(&sConf[0], tp);
        atomicAdd(&sConf[1], lblS);
        atomicAdd(&sConf[2], predS);
    }
    __syncthreads();

    if (t < 3 && sConf[t]) atomicAdd(&counters[t], sConf[t]);
    if (t < 102 && sThr[t]) {
        atomicAdd(&counters[4 + t],   sThr[t] & 0xFFFFu);
        atomicAdd(&counters[106 + t], sThr[t] >> 16);
    }

    // non-atomic flush of the fine histogram (coalesced)
    u32* dst = partials + (size_t)blockIdx.x * K;
    for (int i = t; i < K; i += TPB) dst[i] = fineLDS[i];
}

// fold NB per-block slices -> u64 fineHist (count | pos<<32)
__global__ void __launch_bounds__(CHUNK)
reduce_hist(const u32* __restrict__ partials, int K, int NB,
            u64* __restrict__ fineHist)
{
    const int bin = blockIdx.x * CHUNK + threadIdx.x;
    u32 cnt = 0u, pos = 0u;
    #pragma unroll 8
    for (int b = 0; b < NB; ++b) {
        u32 v = partials[(size_t)b * K + bin];
        cnt += (v & 0xFFFFu);
        pos += (v >> 16);
    }
    fineHist[bin] = (u64)cnt | ((u64)pos << 32);
}

// Sum each descending-order chunk of CHUNK bins -> blockSums[c]
__global__ void __launch_bounds__(CHUNK)
chunk_sums(const u64* __restrict__ fineHist, int K, u64* __restrict__ blockSums)
{
    __shared__ u64 sh[CHUNK];
    const int t = threadIdx.x;
    const int d = blockIdx.x * CHUNK + t;
    sh[t] = (d < K) ? fineHist[K - 1 - d] : 0ULL;
    __syncthreads();
    for (int off = CHUNK / 2; off > 0; off >>= 1) {
        if (t < off) sh[t] += sh[t + off];
        __syncthreads();
    }
    if (t == 0) blockSums[blockIdx.x] = sh[0];
}

// Exclusive scan of blockSums[0..S-1] in place (single block)
__global__ void __launch_bounds__(1024)
scan_sums(u64* __restrict__ blockSums, int S)
{
    __shared__ u64 sh[1024];
    const int t = threadIdx.x;
    u64 own = (t < S) ? blockSums[t] : 0ULL;
    sh[t] = own;
    __syncthreads();
    for (int off = 1; off < 1024; off <<= 1) {
        u64 v = (t >= off) ? sh[t - off] : 0ULL;
        __syncthreads();
        sh[t] += v;
        __syncthreads();
    }
    if (t < S) blockSums[t] = sh[t] - own;
}

// Per-bin AP contributions: descending traversal with exclusive (Nb, Pb)
__global__ void __launch_bounds__(CHUNK)
ap_kernel(const u64* __restrict__ fineHist, int K,
          const u64* __restrict__ blockOffsets, double* __restrict__ apPartial)
{
    __shared__ u64 sh[CHUNK];
    __shared__ double sd[CHUNK];
    const int t = threadIdx.x;
    const int d = blockIdx.x * CHUNK + t;
    u64 h = (d < K) ? fineHist[K - 1 - d] : 0ULL;
    sh[t] = h;
    __syncthreads();
    for (int off = 1; off < CHUNK; off <<= 1) {
        u64 v = (t >= off) ? sh[t - off] : 0ULL;
        __syncthreads();
        sh[t] += v;
        __syncthreads();
    }
    u64 excl = blockOffsets[blockIdx.x] + (sh[t] - h);
    u32 Cv = (u32)h;
    u32 Pv = (u32)(h >> 32);
    float Nb = (float)(u32)excl;          // total count in strictly-higher bins
    float Pb = (float)(u32)(excl >> 32);  // positives in strictly-higher bins
    float contrib = 0.0f;
    if (Pv > 0u) {
        float ratio = (float)Cv / (float)Pv;
        for (u32 j = 1; j <= Pv; ++j) {
            float rank = Nb + ((float)j - 0.5f) * ratio + 0.5f;
            contrib += (Pb + (float)j) / rank;
        }
    }
    sd[t] = (double)contrib;
    __syncthreads();
    for (int off = CHUNK / 2; off > 0; off >>= 1) {
        if (t < off) sd[t] += sd[t + off];
        __syncthreads();
    }
    if (t == 0) apPartial[blockIdx.x] = sd[0];
}

__global__ void __launch_bounds__(128)
finalize(const u32* __restrict__ counters, const double* __restrict__ apPartial, int S,
         const float* __restrict__ loss, int N, float* __restrict__ out)
{
    __shared__ float sIdx[101];
    __shared__ float sFn[101];
    __shared__ float sScal[2]; // totPosF, nF
    const int t = threadIdx.x;
    if (t == 0) {
        u32 tpS = counters[0], lblS = counters[1], predS = counters[2];
        float tp0 = (float)tpS;
        float fn0 = (float)(lblS - tpS);
        float fp0 = (float)(predS - tpS);
        float tn0 = (float)((u32)N - lblS - predS + tpS);
        u32 accA = 0u, accP = 0u;
        for (int k = 0; k <= 100; ++k) {
            accA += counters[4 + k];
            accP += counters[106 + k];
            sIdx[k] = (float)accA;
            sFn[k]  = (float)accP;
        }
        double s = 0.0;
        for (int c = 0; c < S; ++c) s += apPartial[c];
        double denom = (lblS > 0u) ? (double)lblS : 1.0;
        float ap = (float)(s / denom);
        float nF = (float)N;

        out[0] = tn0; out[1] = fp0; out[2] = fn0; out[3] = tp0;
        out[4] = ap;
        out[409] = safe_div_f(tp0, tp0 + fn0);   // recall
        out[410] = safe_div_f(tp0, tp0 + fp0);   // precision
        out[411] = safe_div_f(tn0, tn0 + fp0);   // specificity
        out[412] = (tp0 + tn0) / nF;             // accuracy
        out[413] = (loss[0] + loss[1] + loss[2] + loss[3]) * 0.25f;
        sScal[0] = (float)lblS;
        sScal[1] = nF;
    }
    __syncthreads();
    if (t < 101) {
        float totPos = sScal[0], nF = sScal[1];
        float idx_f = sIdx[t], fn_t = sFn[t];
        float tp_t = totPos - fn_t;
        float tn_t = idx_f - fn_t;
        float fp_t = nF - idx_f - tp_t;
        out[5 + t]   = safe_div_f(tp_t, tp_t + fp_t);  // prec_t
        out[106 + t] = safe_div_f(tp_t, tp_t + fn_t);  // rec_t
        out[207 + t] = (float)t * 0.01f;               // ths
        out[308 + t] = safe_div_f(tn_t, tn_t + fp_t);  // spec_t
    }
}

extern "C" void kernel_launch(void* const* d_in, const int* in_sizes, int n_in,
                              void* d_out, int out_size, void* d_ws, size_t ws_size,
                              hipStream_t stream)
{
    const float* logits  = (const float*)d_in[0];
    const int*   targets = (const int*)d_in[1];
    const float* loss    = (const float*)d_in[2];
    const int N = in_sizes[1];

    // Pick fine-histogram size K (power of two, <= KMAX) that fits workspace.
    int K = KMAX;
    for (;;) {
        int S = K / CHUNK; if (S < 1) S = 1;
        size_t need = (size_t)NBLK * K * 4 + (size_t)K * 8 + (size_t)S * 16 + 832;
        if (need <= ws_size || K <= 2048) break;
        K >>= 1;
    }
    int S = K / CHUNK; if (S < 1) S = 1;

    char* ws = (char*)d_ws;
    u32*    partials  = (u32*)ws;
    u64*    fineHist  = (u64*)(ws + (size_t)NBLK * K * 4);
    u64*    blockSums = (u64*)(ws + (size_t)NBLK * K * 4 + (size_t)K * 8);
    double* apPartial = (double*)(ws + (size_t)NBLK * K * 4 + (size_t)K * 8 + (size_t)S * 8);
    u32*    counters  = (u32*)(ws + (size_t)NBLK * K * 4 + (size_t)K * 8 + (size_t)S * 16);

    hipMemsetAsync(counters, 0, 832, stream);

    main_pass<<<NBLK, TPB, 0, stream>>>(logits, targets, N, partials, K, counters);
    reduce_hist<<<K / CHUNK, CHUNK, 0, stream>>>(partials, K, NBLK, fineHist);
    chunk_sums<<<S, CHUNK, 0, stream>>>(fineHist, K, blockSums);
    scan_sums<<<1, 1024, 0, stream>>>(blockSums, S);
    ap_kernel<<<S, CHUNK, 0, stream>>>(fineHist, K, blockSums, apPartial);
    finalize<<<1, 128, 0, stream>>>(counters, apPartial, S, loss, N, (float*)d_out);
}

// Round 3
// 63.274 us; speedup vs baseline: 13.1902x; 1.6708x over previous
//
#include <hip/hip_runtime.h>

typedef unsigned int u32;
typedef unsigned long long u64;

// ---------------------------------------------------------------------------
// Output layout (float32, 414 elems):
//  [0..3] confmat [tn,fp,fn,tp]; [4] map_; [5..105] prec_t; [106..206] rec_t;
//  [207..307] ths; [308..408] spec_t; [409..413] recall,precision,specificity,
//  accuracy, loss_out
//
// Fine histogram: 4096 bins = 102 threshold-aligned regions x 40 sub-bins.
// Region k holds elements with  (k-1)*0.01f < p1 <= k*0.01f  (exact float
// compares, same fixup as round 2 which validated absmax==0), so threshold
// counts are EXACT prefix sums over whole regions. Sub-bins order elements
// within a region for the AP rank approximation.
//
// Workspace layout:
//  partials: NBLK*K*4 (u32 packed count|pos<<16, per main block)
//  fineHist: K*8      (u64 packed count|pos<<32)
//  counters: 32B      (u32 [0]=tp [1]=lblSum [2]=predSum)
//  prefixD:  K*8      (u64 exclusive descending prefix; d=0 is highest bin)
//  apPartial: APB*8   (double per ap block)
// ---------------------------------------------------------------------------

#define K     4096
#define NBLK  512
#define TPB   1024
#define APB   256

static __device__ __forceinline__ float safe_div_f(float a, float b) {
    return (b > 0.0f) ? (a / fmaxf(b, 1.0f)) : 0.0f;
}

static __device__ __forceinline__ void proc(
    float l0, float l1, int lbl,
    u32& tp, u32& lblS, u32& predS, u32* __restrict__ fineLDS)
{
    float d = l1 - l0;
    u32 pred = (d > 0.0f) ? 1u : 0u;            // argmax: ties -> 0
    float e = __expf(-fabsf(d));                // in (0,1]
    float pl = e / (1.0f + e);                  // min(p1, 1-p1)
    float p1 = pred ? (1.0f - pl) : pl;

    tp    += ((u32)lbl & pred);
    lblS  += (u32)lbl;
    predS += pred;

    // smallest k in [0,101] with p1 <= (float)k * 0.01f ; 101 if none (exact)
    int k = (int)ceilf(p1 * 100.0f);
    k = min(max(k, 0), 101);
    if (k > 0 && p1 <= (float)(k - 1) * 0.01f) --k;
    else if (k <= 100 && p1 > (float)k * 0.01f) ++k;

    // 40 sub-bins within region k (ordering only; need not be exact)
    float lo = (float)(k - 1) * 0.01f;
    int sub = (int)((p1 - lo) * 4000.0f);
    sub = min(max(sub, 0), 39);
    int bin = k * 40 + sub;                     // < 4080 < K

    atomicAdd(&fineLDS[bin], 1u | ((u32)lbl << 16));
}

__global__ void __launch_bounds__(TPB, 8)
main_pass(const float* __restrict__ logits, const int* __restrict__ targets,
          int N, u32* __restrict__ partials, u32* __restrict__ counters)
{
    __shared__ u32 fineLDS[K];
    __shared__ u32 sConf[3];

    const int t = threadIdx.x;
    for (int i = t; i < K; i += TPB) fineLDS[i] = 0u;
    if (t < 3) sConf[t] = 0u;
    __syncthreads();

    const int nPairs = N >> 1;
    const int gid = blockIdx.x * TPB + t;
    const int stride = gridDim.x * TPB;
    const float4* __restrict__ lp = (const float4*)logits;
    const int2*   __restrict__ tg = (const int2*)targets;

    u32 tp = 0u, lblS = 0u, predS = 0u;

    for (int i = gid; i < nPairs; i += stride) {
        float4 v = lp[i];
        int2 lab = tg[i];
        proc(v.x, v.y, lab.x, tp, lblS, predS, fineLDS);
        proc(v.z, v.w, lab.y, tp, lblS, predS, fineLDS);
    }
    if (gid == 0 && (N & 1)) {
        int last = N - 1;
        proc(logits[2 * last], logits[2 * last + 1], targets[last],
             tp, lblS, predS, fineLDS);
    }

    #pragma unroll
    for (int off = 32; off > 0; off >>= 1) {
        tp    += __shfl_down(tp, off);
        lblS  += __shfl_down(lblS, off);
        predS += __shfl_down(predS, off);
    }
    if ((t & 63) == 0) {
        atomicAdd(&sConf[0], tp);
        atomicAdd(&sConf[1], lblS);
        atomicAdd(&sConf[2], predS);
    }
    __syncthreads();
    if (t < 3 && sConf[t]) atomicAdd(&counters[t], sConf[t]);

    // non-atomic coalesced flush
    u32* dst = partials + (size_t)blockIdx.x * K;
    for (int i = t; i < K; i += TPB) dst[i] = fineLDS[i];
}

// Fold NBLK slices into u64 fineHist. grid = 16 chunks x 8 groups = 128 blocks.
__global__ void __launch_bounds__(256)
reduce_hist(const u32* __restrict__ partials, u64* __restrict__ fineHist)
{
    const int chunk = blockIdx.x & 15;
    const int grp   = blockIdx.x >> 4;          // 0..7, 64 slices each
    const int bin = chunk * 256 + threadIdx.x;
    u32 cnt = 0u, pos = 0u;
    const u32* p = partials + (size_t)(grp * 64) * K + bin;
    #pragma unroll 8
    for (int s = 0; s < 64; ++s) {
        u32 v = p[(size_t)s * K];
        cnt += (v & 0xFFFFu);
        pos += (v >> 16);
    }
    atomicAdd(&fineHist[bin], (u64)cnt | ((u64)pos << 32));
}

// Full exclusive descending prefix of fineHist -> prefixD[d], d=0 highest bin.
__global__ void __launch_bounds__(1024)
scan_full(const u64* __restrict__ fineHist, u64* __restrict__ prefixD)
{
    __shared__ u64 sh[1024];
    const int t = threadIdx.x;
    u64 v0 = fineHist[K - 1 - (4 * t + 0)];
    u64 v1 = fineHist[K - 1 - (4 * t + 1)];
    u64 v2 = fineHist[K - 1 - (4 * t + 2)];
    u64 v3 = fineHist[K - 1 - (4 * t + 3)];
    u64 s0 = v0, s1 = s0 + v1, s2 = s1 + v2, s3 = s2 + v3;
    sh[t] = s3;
    __syncthreads();
    for (int off = 1; off < 1024; off <<= 1) {
        u64 v = (t >= off) ? sh[t - off] : 0ULL;
        __syncthreads();
        sh[t] += v;
        __syncthreads();
    }
    u64 excl = sh[t] - s3;
    prefixD[4 * t + 0] = excl;
    prefixD[4 * t + 1] = excl + s0;
    prefixD[4 * t + 2] = excl + s1;
    prefixD[4 * t + 3] = excl + s2;
}

// AP contributions: one wave per 4 bins, lanes parallelize the j-loop.
__global__ void __launch_bounds__(256)
ap_kernel(const u64* __restrict__ fineHist, const u64* __restrict__ prefixD,
          double* __restrict__ apPartial)
{
    __shared__ double sd[4];
    const int t = threadIdx.x;
    const int lane = t & 63;
    const int wave = t >> 6;
    float acc = 0.0f;
    #pragma unroll
    for (int q = 0; q < 4; ++q) {
        int d = blockIdx.x * 16 + wave * 4 + q;
        u64 h = fineHist[K - 1 - d];
        u32 Cv = (u32)h;
        u32 Pv = (u32)(h >> 32);
        if (Pv) {
            u64 e = prefixD[d];
            float Nb = (float)(u32)e;
            float Pb = (float)(u32)(e >> 32);
            float ratio = (float)Cv / (float)Pv;
            for (u32 j = (u32)lane + 1u; j <= Pv; j += 64u) {
                float jf = (float)j;
                float rank = Nb + (jf - 0.5f) * ratio + 0.5f;
                acc += (Pb + jf) / rank;
            }
        }
    }
    double dacc = (double)acc;
    #pragma unroll
    for (int off = 32; off > 0; off >>= 1)
        dacc += __shfl_down(dacc, off);
    if (lane == 0) sd[wave] = dacc;
    __syncthreads();
    if (t == 0) apPartial[blockIdx.x] = sd[0] + sd[1] + sd[2] + sd[3];
}

__global__ void __launch_bounds__(128)
finalize(const u32* __restrict__ counters, const u64* __restrict__ prefixD,
         const double* __restrict__ apPartial,
         const float* __restrict__ loss, int N, float* __restrict__ out)
{
    __shared__ double sd[128];
    const int t = threadIdx.x;
    sd[t] = apPartial[t] + apPartial[t + 128];
    __syncthreads();
    for (int off = 64; off > 0; off >>= 1) {
        if (t < off) sd[t] += sd[t + off];
        __syncthreads();
    }

    const u32 tpS = counters[0], lblS = counters[1], predS = counters[2];
    const float nF = (float)N;

    if (t <= 100) {
        // elements / positives in regions > t (i.e. p1 > th_t), exact
        u64 pv = prefixD[K - (t + 1) * 40];
        float above  = (float)(u32)pv;
        float aboveP = (float)(u32)(pv >> 32);
        float totPos = (float)lblS;
        float idx_f = nF - above;
        float tp_t = aboveP;
        float fn_t = totPos - aboveP;
        float tn_t = idx_f - fn_t;
        float fp_t = nF - idx_f - tp_t;
        out[5 + t]   = safe_div_f(tp_t, tp_t + fp_t);  // prec_t
        out[106 + t] = safe_div_f(tp_t, tp_t + fn_t);  // rec_t
        out[207 + t] = (float)t * 0.01f;               // ths
        out[308 + t] = safe_div_f(tn_t, tn_t + fp_t);  // spec_t
    }

    if (t == 0) {
        float tp0 = (float)tpS;
        float fn0 = (float)(lblS - tpS);
        float fp0 = (float)(predS - tpS);
        float tn0 = (float)((u32)N - lblS - predS + tpS);
        double denom = (lblS > 0u) ? (double)lblS : 1.0;
        out[0] = tn0; out[1] = fp0; out[2] = fn0; out[3] = tp0;
        out[4] = (float)(sd[0] / denom);
        out[409] = safe_div_f(tp0, tp0 + fn0);
        out[410] = safe_div_f(tp0, tp0 + fp0);
        out[411] = safe_div_f(tn0, tn0 + fp0);
        out[412] = (tp0 + tn0) / nF;
        out[413] = (loss[0] + loss[1] + loss[2] + loss[3]) * 0.25f;
    }
}

extern "C" void kernel_launch(void* const* d_in, const int* in_sizes, int n_in,
                              void* d_out, int out_size, void* d_ws, size_t ws_size,
                              hipStream_t stream)
{
    const float* logits  = (const float*)d_in[0];
    const int*   targets = (const int*)d_in[1];
    const float* loss    = (const float*)d_in[2];
    const int N = in_sizes[1];

    char* ws = (char*)d_ws;
    size_t off = 0;
    u32* partials = (u32*)(ws + off);   off += (size_t)NBLK * K * 4;   // 8 MB
    u64* fineHist = (u64*)(ws + off);   off += (size_t)K * 8;          // 32 KB
    u32* counters = (u32*)(ws + off);   off += 32;
    u64* prefixD  = (u64*)(ws + off);   off += (size_t)K * 8;          // 32 KB
    double* apPartial = (double*)(ws + off);                           // 2 KB

    // zero fineHist + counters (contiguous span)
    hipMemsetAsync(fineHist, 0, (size_t)K * 8 + 32, stream);

    main_pass<<<NBLK, TPB, 0, stream>>>(logits, targets, N, partials, counters);
    reduce_hist<<<128, 256, 0, stream>>>(partials, fineHist);
    scan_full<<<1, 1024, 0, stream>>>(fineHist, prefixD);
    ap_kernel<<<APB, 256, 0, stream>>>(fineHist, prefixD, apPartial);
    finalize<<<1, 128, 0, stream>>>(counters, prefixD, apPartial, loss, N, (float*)d_out);
}